// Round 6
// baseline (1741.383 us; speedup 1.0000x reference)
//
#include <hip/hip_runtime.h>

#define DD 12
#define VOX 1728
#define BN_EPS 1e-5f
#define BATCH 512
#define PER 864
#define PERZ 865                                  // PER + 1 zero row per batch
#define NTOT (BATCH * PER)                        // 442368 points

typedef __attribute__((ext_vector_type(8))) short short8;   // 8 bf16 = 16B
typedef __attribute__((ext_vector_type(4))) float f32x4;
typedef unsigned short u16;

__device__ inline u16 f2b(float f) {              // fp32 -> bf16 RNE
    union { float f; unsigned u; } v; v.f = f;
    unsigned r = v.u + 0x7fffu + ((v.u >> 16) & 1u);
    return (u16)(r >> 16);
}
__device__ inline float b2f(u16 h) {
    union { unsigned u; float f; } v; v.u = ((unsigned)h) << 16;
    return v.f;
}
constexpr int ilog2(int v) { return v == 1 ? 0 : 1 + ilog2(v / 2); }

__device__ __forceinline__ void async_copy16(const void* g, void* l) {
    __builtin_amdgcn_global_load_lds(
        (const __attribute__((address_space(1))) void*)g,
        (__attribute__((address_space(3))) void*)l, 16, 0, 0);
}

// counted vmcnt wait; memory clobber pins memory-op motion across it
template<int N> __device__ __forceinline__ void wait_vm() {
    if constexpr (N == 0)       asm volatile("s_waitcnt vmcnt(0)"  ::: "memory");
    else if constexpr (N == 4)  asm volatile("s_waitcnt vmcnt(4)"  ::: "memory");
    else if constexpr (N == 8)  asm volatile("s_waitcnt vmcnt(8)"  ::: "memory");
    else if constexpr (N == 16) asm volatile("s_waitcnt vmcnt(16)" ::: "memory");
    else static_assert(N == 0, "unhandled vmcnt value");
}

// ---------------- voxel -> point-row map ----------------
__global__ void build_map_kernel(const int* __restrict__ idx, int* __restrict__ map, int N) {
    int p = blockIdx.x * blockDim.x + threadIdx.x;
    if (p >= N) return;
    const int4 v = ((const int4*)idx)[p];
    map[v.x * VOX + (v.y * DD + v.z) * DD + v.w] = p;
}

// ---------------- neighbor table, TAP-MAJOR: nbr[tap][point] ----------------
__global__ void build_nbr_kernel(const int* __restrict__ idx, const int* __restrict__ map,
                                 u16* __restrict__ nbr, int N) {
    int p = blockIdx.x * blockDim.x + threadIdx.x;
    if (p >= N) return;
    const int4 v = ((const int4*)idx)[p];
    const int base = v.x * VOX;
    const int lb = v.x * PER;
    #pragma unroll
    for (int nk = 0; nk < 27; nk++) {
        int dz = nk / 9 - 1, dy = (nk / 3) % 3 - 1, dx = nk % 3 - 1;
        int zz = v.y + dz, yy = v.z + dy, xx = v.w + dx;
        u16 out = PER;
        if (zz >= 0 && zz < DD && yy >= 0 && yy < DD && xx >= 0 && xx < DD) {
            int q = map[base + (zz * DD + yy) * DD + xx];
            if (q >= 0) out = (u16)(q - lb);
        }
        nbr[nk * N + p] = out;
    }
    #pragma unroll
    for (int nk = 27; nk < 32; nk++) nbr[nk * N + p] = PER;
}

// ---------------- pack W [K][COUT] fp32 into per-lane MFMA fragment order ----------------
// Wp layout: elem16-index t = ((step*NG + g)*8 + sj)*64 + lane, each entry 8 bf16 (16B).
// Fragment (g, sj=s*4+j, lane): col = g*64 + j*16 + (lane&15),
//                               k   = step*64 + s*32 + (lane>>4)*8 + e.  k>=K -> 0.
template<int CIN, int COUT>
__global__ void pack_w_kernel(const float* __restrict__ W, u16* __restrict__ Wp) {
    constexpr int K = 27 * CIN;
    constexpr int KSTEPS = ((K + 63) & ~63) / 64;
    constexpr int NG = COUT / 64;
    int t = blockIdx.x * blockDim.x + threadIdx.x;
    if (t >= KSTEPS * NG * 8 * 64) return;
    int lane = t & 63;
    int sj   = (t >> 6) & 7;
    int gg   = t >> 9;                            // step*NG + g
    int g = gg % NG, step = gg / NG;
    int col = g * 64 + (sj & 3) * 16 + (lane & 15);
    int k0  = step * 64 + (sj >> 2) * 32 + (lane >> 4) * 8;
    short8 o;
    #pragma unroll
    for (int e = 0; e < 8; e++) {
        int k = k0 + e;
        u16 val = 0;
        if (k < K) val = f2b(W[(size_t)k * COUT + col]);
        ((u16*)&o)[e] = val;
    }
    *(short8*)(Wp + (size_t)t * 8) = o;
}

// ---------------- zero the per-batch zero rows of a feature buffer ----------------
__global__ void zero_rows_kernel(u16* __restrict__ f, int CIN) {
    int t = blockIdx.x * blockDim.x + threadIdx.x;          // over BATCH*CIN/4
    int e4 = CIN >> 2;
    if (t >= BATCH * e4) return;
    int b = t / e4, k = t - b * e4;
    ((ushort4*)f)[(size_t)(b * PERZ + PER) * e4 + k] = make_ushort4(0, 0, 0, 0);
}

// ---------------- fp32 feats -> bf16, strided (PERZ) layout ----------------
__global__ void cast_bf16_kernel(const float* __restrict__ in, u16* __restrict__ out, int N4) {
    int i = blockIdx.x * blockDim.x + threadIdx.x;          // over N*4 (float4 groups, CIN=16)
    if (i >= N4) return;
    float4 v = ((const float4*)in)[i];
    int p = i >> 2, c4 = i & 3;
    int b = p / PER, r = p - b * PER;
    ushort4 o;
    o.x = f2b(v.x); o.y = f2b(v.y); o.z = f2b(v.z); o.w = f2b(v.w);
    ((ushort4*)out)[(size_t)(b * PERZ + r) * 4 + c4] = o;
}

// ---------------- implicit-GEMM conv: BM=128, 4 M-stacked waves, occupancy-first ----------
// Wave tile 32x64 (acc 2x4, 32 VGPR), A dbuf 32KB LDS, B single-buffered in registers.
// Target 4-5 resident blocks/CU (vs 2 at BM=256) to hide the per-step latency chain.
// COUT=128 splits col-groups across the grid (colg = post-swizzle bid&1 so the pair
// sharing A rows lands on the same XCD/L2). Counted vmcnt; raw s_barrier; never
// vmcnt(0) mid-loop.
template<int CIN, int COUT, int BM>
__global__ __launch_bounds__(256) void conv_mfma_kernel(
    const u16* __restrict__ fin,      // (BATCH*PERZ) x CIN bf16 (zero row per batch)
    const u16* __restrict__ nbr,      // 32 x NTOT u16 (tap-major)
    const u16* __restrict__ Wp,       // packed fragment-order weights
    const float* __restrict__ bias,
    float* __restrict__ y,
    float* __restrict__ stats) {
    constexpr int Kpad   = (27 * CIN + 63) & ~63;
    constexpr int KSTEPS = Kpad / 64;
    constexpr int L2C    = ilog2(CIN);
    constexpr int NG     = COUT / 64;             // col-groups (grid-split)
    constexpr int ASLOTS = BM / 32;               // per-thread 16B DMA slots for A (=4)
    constexpr int BUFB   = BM * 128;              // one A buffer (BM rows x 128B) = 16KB
    static_assert(KSTEPS >= 3, "pipeline prologue needs >=3 K-steps");
    __shared__ char smem[2 * BUFB];               // A double-buffer only (32KB)

    // XCD-contiguous swizzle (grid % 8 == 0), then col-group decode
    const int perx = gridDim.x >> 3;
    const int bid = (blockIdx.x & 7) * perx + (blockIdx.x >> 3);
    const int colg = (NG > 1) ? (bid & (NG - 1)) : 0;
    const int rowb = (NG > 1) ? (bid >> (NG > 1 ? 1 : 0)) : bid;
    const int p0 = rowb * BM;

    const int tid = threadIdx.x;
    const int wave = tid >> 6, lane = tid & 63;
    const int wm = wave;                          // 4 waves stacked in M, 32 rows each
    const int lq = lane >> 4, lr = lane & 15;
    const int lrow = lane >> 3;                   // DMA row within 8-row group
    const int kc_d = (lane & 7) ^ (lrow & 7);     // swizzled chunk this lane fetches

    // ---- A staging invariants ----
    const int qv0 = ((((kc_d * 8) >> L2C) * NTOT) + p0 + wave * ASLOTS * 8 + lrow) * 2;
    int gbase[ASLOTS];
    #pragma unroll
    for (int i = 0; i < ASLOTS; i++) {
        int p = p0 + (wave * ASLOTS + i) * 8 + lrow;
        int b = p / PER;
        gbase[i] = b * PERZ * CIN + ((kc_d * 8) & (CIN - 1));   // elems into fin
    }

    // A fragment read addrs: physical chunk = logical ^ (row&7)
    const int phs0 = ((0 + lq) ^ (lr & 7)) * 16;
    const int phs1 = ((4 + lq) ^ (lr & 7)) * 16;
    const int aBase = (wm * 32 + lr) * 128;

    const f32x4 fzero = {0.f, 0.f, 0.f, 0.f};
    f32x4 acc[2][4];
    #pragma unroll
    for (int i = 0; i < 2; i++)
        #pragma unroll
        for (int j = 0; j < 4; j++) acc[i][j] = fzero;

    u16 q[ASLOTS];
    short8 bb[8];
    auto loadQ = [&](int step) {
        int sQ = qv0 + ((step * 64) >> L2C) * (NTOT * 2);       // tap-major stride
        #pragma unroll
        for (int i = 0; i < ASLOTS; i++)
            q[i] = *(const u16*)((const char*)nbr + sQ + i * 16);
    };
    auto stage = [&](int step, int bo) {
        int sG = (step * 64) & (CIN - 1);
        const u16* fs = fin + sG;
        #pragma unroll
        for (int i = 0; i < ASLOTS; i++)
            async_copy16(fs + gbase[i] + ((int)q[i] << L2C),
                         smem + bo + (wave * ASLOTS + i) * 1024);
    };
    const char* wpB = (const char*)Wp + (size_t)colg * 8 * 1024 + (size_t)lane * 16;
    auto loadB = [&](int step) {
        const char* src = wpB + (size_t)step * (NG * 8 * 1024);
        #pragma unroll
        for (int sj = 0; sj < 8; sj++)
            bb[sj] = *(const short8*)(src + sj * 1024);
    };
    auto compute = [&](int so) {
        #pragma unroll
        for (int s = 0; s < 2; s++) {
            const int ph = s ? phs1 : phs0;
            short8 af[2];
            #pragma unroll
            for (int i = 0; i < 2; i++)
                af[i] = *(const short8*)(smem + so + aBase + i * 2048 + ph);
            #pragma unroll
            for (int i = 0; i < 2; i++)
                #pragma unroll
                for (int j = 0; j < 4; j++)
                    acc[i][j] = __builtin_amdgcn_mfma_f32_16x16x32_bf16(af[i], bb[s * 4 + j], acc[i][j], 0, 0, 0);
        }
    };

    // ---- pipeline prologue ----
    loadQ(0);
    stage(0, 0);                                  // buf0 <- A step 0
    loadB(0);                                     // bb  <- B step 0
    loadQ(1);                                     // ids for step 1 (in flight)

    #pragma unroll 1
    for (int kb = 0; kb < KSTEPS; kb++) {
        // issue next-step A prefetch, then counted wait: drains A(kb) DMA, B(kb) regs,
        // q(kb+1); leaves stage(kb+1)+loadQ(kb+2) in flight across the barrier.
        if (kb + 1 < KSTEPS) {
            stage(kb + 1, ((kb + 1) & 1) * BUFB); // q-dep: q[] regs hold step kb+1 ids
            if (kb + 2 < KSTEPS) {
                loadQ(kb + 2);
                wait_vm<2 * ASLOTS>();            // ASLOTS (stage) + ASLOTS (loadQ)
            } else {
                wait_vm<ASLOTS>();
            }
        } else {
            wait_vm<0>();                         // last step: drain everything
        }
        __builtin_amdgcn_s_barrier();             // A(kb) landed block-wide

        compute((kb & 1) * BUFB);                 // reads LDS A(kb) + regs B(kb)

        // refill bb with B(kb+1) AFTER its last read; sched_barrier pins the order so
        // the compiler cannot hoist/rename these loads into a second register buffer.
        __builtin_amdgcn_sched_barrier(0);
        if (kb + 1 < KSTEPS) loadB(kb + 1);

        asm volatile("s_waitcnt lgkmcnt(0)" ::: "memory");  // all ds_reads retired
        __builtin_amdgcn_s_barrier();             // A buf free for overwrite
    }

    // ---- epilogue: bias, store y, fused per-channel sum/sumsq ----
    #pragma unroll
    for (int j = 0; j < 4; j++) {
        int col = colg * 64 + j * 16 + lr;
        float bv = bias[col];
        float s = 0.f, s2 = 0.f;
        #pragma unroll
        for (int i = 0; i < 2; i++) {
            int row0 = p0 + wm * 32 + i * 16 + lq * 4;
            #pragma unroll
            for (int r = 0; r < 4; r++) {
                float v = acc[i][j][r] + bv;
                y[(size_t)(row0 + r) * COUT + col] = v;
                s += v; s2 += v * v;
            }
        }
        s  += __shfl_down(s, 32);  s  += __shfl_down(s, 16);
        s2 += __shfl_down(s2, 32); s2 += __shfl_down(s2, 16);
        if (lane < 16) {
            atomicAdd(&stats[col], s);
            atomicAdd(&stats[COUT + col], s2);
        }
    }
}

// ---------------- fold BN into scale/shift ----------------
template<int COUT>
__global__ void finalize_kernel(const float* __restrict__ stats, const float* __restrict__ gamma,
                                const float* __restrict__ beta, float* __restrict__ ss, int N) {
    int co = threadIdx.x;
    float inv_n = 1.f / (float)N;
    float mu  = stats[co] * inv_n;
    float var = stats[COUT + co] * inv_n - mu * mu;
    float sc  = gamma[co] * rsqrtf(var + BN_EPS);
    ss[co]        = sc;
    ss[COUT + co] = beta[co] - mu * sc;
}

// ---------------- BN + ReLU, emit bf16 into strided (PERZ) layout ----------------
template<int COUT>
__global__ void apply_kernel(const float* __restrict__ y, const float* __restrict__ ss,
                             u16* __restrict__ f, int total4) {
    int i = blockIdx.x * blockDim.x + threadIdx.x;
    if (i >= total4) return;
    constexpr int E4 = COUT / 4;
    float4 v = ((const float4*)y)[i];
    int p = i / E4, k = i - p * E4;
    int c0 = k * 4;
    int b = p / PER, r = p - b * PER;
    ushort4 o;
    float a;
    a = fmaf(v.x, ss[c0 + 0], ss[COUT + c0 + 0]); o.x = f2b(a > 0.f ? a : 0.f);
    a = fmaf(v.y, ss[c0 + 1], ss[COUT + c0 + 1]); o.y = f2b(a > 0.f ? a : 0.f);
    a = fmaf(v.z, ss[c0 + 2], ss[COUT + c0 + 2]); o.z = f2b(a > 0.f ? a : 0.f);
    a = fmaf(v.w, ss[c0 + 3], ss[COUT + c0 + 3]); o.w = f2b(a > 0.f ? a : 0.f);
    ((ushort4*)f)[(size_t)(b * PERZ + r) * E4 + k] = o;
}

// ---------------- dense NCDHW output ----------------
__global__ void output_kernel(const u16* __restrict__ f, const int* __restrict__ map,
                              float* __restrict__ out, int total) {
    int i = blockIdx.x * blockDim.x + threadIdx.x;
    if (i >= total) return;
    int voxel = i % VOX;
    int bc    = i / VOX;
    int c = bc & 63;
    int b = bc >> 6;
    int p = map[b * VOX + voxel];
    float v = 0.f;
    if (p >= 0) {
        int r = p - b * PER;
        v = b2f(f[(size_t)(b * PERZ + r) * 64 + c]);
    }
    out[i] = v;
}

extern "C" void kernel_launch(void* const* d_in, const int* in_sizes, int n_in,
                              void* d_out, int out_size, void* d_ws, size_t ws_size,
                              hipStream_t stream) {
    const float* feats = (const float*)d_in[0];
    const int*   idx   = (const int*)  d_in[1];
    const float* W0 = (const float*)d_in[3];
    const float* b0 = (const float*)d_in[4];
    const float* g0 = (const float*)d_in[5];
    const float* e0 = (const float*)d_in[6];
    const float* W1 = (const float*)d_in[7];
    const float* b1 = (const float*)d_in[8];
    const float* g1 = (const float*)d_in[9];
    const float* e1 = (const float*)d_in[10];
    const float* W2 = (const float*)d_in[11];
    const float* b2 = (const float*)d_in[12];
    const float* g2 = (const float*)d_in[13];
    const float* e2 = (const float*)d_in[14];

    const int N = in_sizes[0] / 16;               // 442368

    // ---- workspace layout ----
    char* ws = (char*)d_ws;
    size_t off = 0;
    auto alloc = [&](size_t bytes) { void* p = ws + off; off = (off + bytes + 255) & ~(size_t)255; return p; };
    int*   map   = (int*)  alloc((size_t)BATCH * VOX * 4);
    float* stats = (float*)alloc(3 * 256 * 4);
    float* ss    = (float*)alloc(3 * 256 * 4);
    u16*   nbr   = (u16*)  alloc((size_t)N * 32 * 2);
    u16*   wt0   = (u16*)  alloc((size_t)7  * 1 * 512 * 16);    // packed: KSTEPS*NG*512*16B
    u16*   wt1   = (u16*)  alloc((size_t)27 * 2 * 512 * 16);
    u16*   wt2   = (u16*)  alloc((size_t)54 * 1 * 512 * 16);
    u16*   fbuf  = (u16*)  alloc((size_t)BATCH * PERZ * 128 * 2);   // shared by all layers
    float* y = (float*)d_out;                     // fp32 conv out, aliases d_out

    hipMemsetAsync(map,   0xFF, (size_t)BATCH * VOX * 4, stream);
    hipMemsetAsync(stats, 0,    3 * 256 * 4, stream);
    build_map_kernel<<<(N + 255) / 256, 256, 0, stream>>>(idx, map, N);
    build_nbr_kernel<<<(N + 255) / 256, 256, 0, stream>>>(idx, map, nbr, N);
    pack_w_kernel<16,  64 ><<<(7  * 1 * 512 + 255) / 256, 256, 0, stream>>>(W0, wt0);
    pack_w_kernel<64,  128><<<(27 * 2 * 512 + 255) / 256, 256, 0, stream>>>(W1, wt1);
    pack_w_kernel<128, 64 ><<<(54 * 1 * 512 + 255) / 256, 256, 0, stream>>>(W2, wt2);

    // ---- layer 1: 16 -> 64 (BM=128, 4 waves, acc 2x4) ----
    zero_rows_kernel<<<(BATCH * 4 + 255) / 256, 256, 0, stream>>>(fbuf, 16);
    cast_bf16_kernel<<<(N * 4 + 255) / 256, 256, 0, stream>>>(feats, fbuf, N * 4);
    conv_mfma_kernel<16, 64, 128><<<N / 128, 256, 0, stream>>>(fbuf, nbr, wt0, b0, y, stats + 0);
    finalize_kernel<64><<<1, 64, 0, stream>>>(stats + 0, g0, e0, ss + 0, N);
    zero_rows_kernel<<<(BATCH * 16 + 255) / 256, 256, 0, stream>>>(fbuf, 64);
    apply_kernel<64><<<(N * 16 + 255) / 256, 256, 0, stream>>>(y, ss + 0, fbuf, N * 16);

    // ---- layer 2: 64 -> 128 (BM=128, col-group split grid x2) ----
    conv_mfma_kernel<64, 128, 128><<<(N / 128) * 2, 256, 0, stream>>>(fbuf, nbr, wt1, b1, y, stats + 256);
    finalize_kernel<128><<<1, 128, 0, stream>>>(stats + 256, g1, e1, ss + 256, N);
    zero_rows_kernel<<<(BATCH * 32 + 255) / 256, 256, 0, stream>>>(fbuf, 128);
    apply_kernel<128><<<(N * 32 + 255) / 256, 256, 0, stream>>>(y, ss + 256, fbuf, N * 32);

    // ---- layer 3: 128 -> 64 (BM=128, 4 waves, acc 2x4) ----
    conv_mfma_kernel<128, 64, 128><<<N / 128, 256, 0, stream>>>(fbuf, nbr, wt2, b2, y, stats + 512);
    finalize_kernel<64><<<1, 64, 0, stream>>>(stats + 512, g2, e2, ss + 512, N);
    zero_rows_kernel<<<(BATCH * 16 + 255) / 256, 256, 0, stream>>>(fbuf, 64);
    apply_kernel<64><<<(N * 16 + 255) / 256, 256, 0, stream>>>(y, ss + 512, fbuf, N * 16);

    // ---- dense NCDHW output ----
    output_kernel<<<(out_size + 255) / 256, 256, 0, stream>>>(fbuf, map, (float*)d_out, out_size);
}

// Round 7
// 1400.849 us; speedup vs baseline: 1.2431x; 1.2431x over previous
//
#include <hip/hip_runtime.h>

#define DD 12
#define VOX 1728
#define BN_EPS 1e-5f
#define BATCH 512
#define PER 864
#define PERZ 865                                  // PER + 1 zero row per batch
#define NTOT (BATCH * PER)                        // 442368 points

typedef __attribute__((ext_vector_type(8))) short short8;   // 8 bf16 = 16B
typedef __attribute__((ext_vector_type(4))) float f32x4;
typedef unsigned short u16;

__device__ inline u16 f2b(float f) {              // fp32 -> bf16 RNE
    union { float f; unsigned u; } v; v.f = f;
    unsigned r = v.u + 0x7fffu + ((v.u >> 16) & 1u);
    return (u16)(r >> 16);
}
__device__ inline float b2f(u16 h) {
    union { unsigned u; float f; } v; v.u = ((unsigned)h) << 16;
    return v.f;
}
constexpr int ilog2(int v) { return v == 1 ? 0 : 1 + ilog2(v / 2); }

__device__ __forceinline__ void async_copy16(const void* g, void* l) {
    __builtin_amdgcn_global_load_lds(
        (const __attribute__((address_space(1))) void*)g,
        (__attribute__((address_space(3))) void*)l, 16, 0, 0);
}

__device__ __forceinline__ void wait_vm0() {
    asm volatile("s_waitcnt vmcnt(0)" ::: "memory");
}

// ---------------- voxel -> point-row map ----------------
__global__ void build_map_kernel(const int* __restrict__ idx, int* __restrict__ map, int N) {
    int p = blockIdx.x * blockDim.x + threadIdx.x;
    if (p >= N) return;
    const int4 v = ((const int4*)idx)[p];
    map[v.x * VOX + (v.y * DD + v.z) * DD + v.w] = p;
}

// ---------------- neighbor table, TAP-MAJOR: nbr[tap][point] ----------------
__global__ void build_nbr_kernel(const int* __restrict__ idx, const int* __restrict__ map,
                                 u16* __restrict__ nbr, int N) {
    int p = blockIdx.x * blockDim.x + threadIdx.x;
    if (p >= N) return;
    const int4 v = ((const int4*)idx)[p];
    const int base = v.x * VOX;
    const int lb = v.x * PER;
    #pragma unroll
    for (int nk = 0; nk < 27; nk++) {
        int dz = nk / 9 - 1, dy = (nk / 3) % 3 - 1, dx = nk % 3 - 1;
        int zz = v.y + dz, yy = v.z + dy, xx = v.w + dx;
        u16 out = PER;
        if (zz >= 0 && zz < DD && yy >= 0 && yy < DD && xx >= 0 && xx < DD) {
            int q = map[base + (zz * DD + yy) * DD + xx];
            if (q >= 0) out = (u16)(q - lb);
        }
        nbr[nk * N + p] = out;
    }
    #pragma unroll
    for (int nk = 27; nk < 32; nk++) nbr[nk * N + p] = PER;
}

// ---------------- pack W [K][COUT] fp32 into per-lane MFMA fragment order ----------------
// Wp layout: elem16-index t = ((step*NG + g)*8 + sj)*64 + lane, each entry 8 bf16 (16B).
// Fragment (g, sj=s*4+j, lane): col = g*64 + j*16 + (lane&15),
//                               k   = step*64 + s*32 + (lane>>4)*8 + e.  k>=K -> 0.
template<int CIN, int COUT>
__global__ void pack_w_kernel(const float* __restrict__ W, u16* __restrict__ Wp) {
    constexpr int K = 27 * CIN;
    constexpr int KSTEPS = ((K + 63) & ~63) / 64;
    constexpr int NG = COUT / 64;
    int t = blockIdx.x * blockDim.x + threadIdx.x;
    if (t >= KSTEPS * NG * 8 * 64) return;
    int lane = t & 63;
    int sj   = (t >> 6) & 7;
    int gg   = t >> 9;                            // step*NG + g
    int g = gg % NG, step = gg / NG;
    int col = g * 64 + (sj & 3) * 16 + (lane & 15);
    int k0  = step * 64 + (sj >> 2) * 32 + (lane >> 4) * 8;
    short8 o;
    #pragma unroll
    for (int e = 0; e < 8; e++) {
        int k = k0 + e;
        u16 val = 0;
        if (k < K) val = f2b(W[(size_t)k * COUT + col]);
        ((u16*)&o)[e] = val;
    }
    *(short8*)(Wp + (size_t)t * 8) = o;
}

// ---------------- zero the per-batch zero rows of a feature buffer ----------------
__global__ void zero_rows_kernel(u16* __restrict__ f, int CIN) {
    int t = blockIdx.x * blockDim.x + threadIdx.x;          // over BATCH*CIN/4
    int e4 = CIN >> 2;
    if (t >= BATCH * e4) return;
    int b = t / e4, k = t - b * e4;
    ((ushort4*)f)[(size_t)(b * PERZ + PER) * e4 + k] = make_ushort4(0, 0, 0, 0);
}

// ---------------- fp32 feats -> bf16, strided (PERZ) layout ----------------
__global__ void cast_bf16_kernel(const float* __restrict__ in, u16* __restrict__ out, int N4) {
    int i = blockIdx.x * blockDim.x + threadIdx.x;          // over N*4 (float4 groups, CIN=16)
    if (i >= N4) return;
    float4 v = ((const float4*)in)[i];
    int p = i >> 2, c4 = i & 3;
    int b = p / PER, r = p - b * PER;
    ushort4 o;
    o.x = f2b(v.x); o.y = f2b(v.y); o.z = f2b(v.z); o.w = f2b(v.w);
    ((ushort4*)out)[(size_t)(b * PERZ + r) * 4 + c4] = o;
}

// ---------------- implicit-GEMM conv: SINGLE-SYNC double-buffered K-loop ----------------
// A via global_load_lds (dbuf LDS), B (weights) single-buffered in registers from
// fragment-order packed Wp. One barrier per step: a wave's ds_reads are consumed
// (lgkmcnt forced by MFMA operands) before it reaches the barrier, so the same barrier
// that publishes stage(kb) also protects buf[(kb+1)&1] against overwrite.
//   vmcnt(0); s_barrier; stage(kb+1)->buf^1; loadQ(kb+2); compute(kb); loadB(kb+1)
// All prefetches get a ~full-iteration flight window; vmcnt(0) drains only loads that
// are needed immediately after it.
template<int CIN, int COUT, int BM, int WM, int WN>
__global__ __launch_bounds__(256) void conv_mfma_kernel(
    const u16* __restrict__ fin,      // (BATCH*PERZ) x CIN bf16 (zero row per batch)
    const u16* __restrict__ nbr,      // 32 x NTOT u16 (tap-major)
    const u16* __restrict__ Wp,       // packed fragment-order weights
    const float* __restrict__ bias,
    float* __restrict__ y,
    float* __restrict__ stats) {
    constexpr int Kpad   = (27 * CIN + 63) & ~63;
    constexpr int KSTEPS = Kpad / 64;
    constexpr int L2C    = ilog2(CIN);
    constexpr int NG     = COUT / 64;
    constexpr int ASLOTS = BM / 32;               // per-thread 16B DMA slots for A
    constexpr int BUFB   = BM * 128;              // one A buffer (BM rows x 128B)
    static_assert(KSTEPS >= 3, "pipeline prologue needs >=3 K-steps");
    __shared__ char smem[2 * BUFB];               // A double-buffer only

    // XCD-contiguous swizzle
    const int perx = gridDim.x >> 3;
    const int bid = (blockIdx.x & 7) * perx + (blockIdx.x >> 3);
    const int p0 = bid * BM;

    const int tid = threadIdx.x;
    const int wave = tid >> 6, lane = tid & 63;
    const int wm = wave / WN, wn = wave % WN;     // 64x64 wave tile at (wm*64, wn*64)
    const int lq = lane >> 4, lr = lane & 15;
    const int lrow = lane >> 3;                   // DMA row within 8-row group
    const int kc_d = (lane & 7) ^ (lrow & 7);     // swizzled chunk this lane fetches

    // ---- A staging invariants ----
    const int qv0 = ((((kc_d * 8) >> L2C) * NTOT) + p0 + wave * ASLOTS * 8 + lrow) * 2;
    int gbase[ASLOTS];
    #pragma unroll
    for (int i = 0; i < ASLOTS; i++) {
        int p = p0 + (wave * ASLOTS + i) * 8 + lrow;
        int b = p / PER;
        gbase[i] = b * PERZ * CIN + ((kc_d * 8) & (CIN - 1));   // elems into fin
    }

    // A fragment read addrs: physical chunk = logical ^ (row&7)
    const int phs0 = ((0 + lq) ^ (lr & 7)) * 16;
    const int phs1 = ((4 + lq) ^ (lr & 7)) * 16;
    const int aBase = (wm * 64 + lr) * 128;

    const f32x4 fzero = {0.f, 0.f, 0.f, 0.f};
    f32x4 acc[4][4];
    #pragma unroll
    for (int i = 0; i < 4; i++)
        #pragma unroll
        for (int j = 0; j < 4; j++) acc[i][j] = fzero;

    u16 q[ASLOTS];
    short8 bb[8];
    auto loadQ = [&](int step) {
        int sQ = qv0 + ((step * 64) >> L2C) * (NTOT * 2);       // tap-major stride
        #pragma unroll
        for (int i = 0; i < ASLOTS; i++)
            q[i] = *(const u16*)((const char*)nbr + sQ + i * 16);
    };
    auto stage = [&](int step, int bo) {
        int sG = (step * 64) & (CIN - 1);
        const u16* fs = fin + sG;
        #pragma unroll
        for (int i = 0; i < ASLOTS; i++)
            async_copy16(fs + gbase[i] + ((int)q[i] << L2C),
                         smem + bo + (wave * ASLOTS + i) * 1024);
    };
    const char* wpB = (const char*)Wp + (size_t)wn * 8 * 1024 + (size_t)lane * 16;
    auto loadB = [&](int step) {
        const char* src = wpB + (size_t)step * (NG * 8 * 1024);
        #pragma unroll
        for (int sj = 0; sj < 8; sj++)
            bb[sj] = *(const short8*)(src + sj * 1024);
    };
    auto compute = [&](int so) {
        #pragma unroll
        for (int s = 0; s < 2; s++) {
            const int ph = s ? phs1 : phs0;
            short8 af[4];
            #pragma unroll
            for (int i = 0; i < 4; i++)
                af[i] = *(const short8*)(smem + so + aBase + i * 2048 + ph);
            #pragma unroll
            for (int i = 0; i < 4; i++)
                #pragma unroll
                for (int j = 0; j < 4; j++)
                    acc[i][j] = __builtin_amdgcn_mfma_f32_16x16x32_bf16(af[i], bb[s * 4 + j], acc[i][j], 0, 0, 0);
        }
    };

    // ---- pipeline prologue ----
    loadQ(0);
    stage(0, 0);                                  // buf0 <- A step 0
    loadB(0);                                     // bb  <- B step 0
    if constexpr (CIN != 128) loadQ(1);           // CIN=128: steps 0,1 share tap-0 ids

    #pragma unroll 1
    for (int kb = 0; kb < KSTEPS; kb++) {
        wait_vm0();                               // own stage(kb)+loadB(kb) landed
        __builtin_amdgcn_s_barrier();             // publish A(kb); buf[(kb+1)&1] free
        __builtin_amdgcn_sched_barrier(0);
        if (kb + 1 < KSTEPS)
            stage(kb + 1, ((kb + 1) & 1) * BUFB); // q holds ids(kb+1)
        if constexpr (CIN == 128) {               // taps advance every 2 steps
            if (!(kb & 1) && kb + 2 < KSTEPS) loadQ(kb + 2);
        } else {
            if (kb + 2 < KSTEPS) loadQ(kb + 2);
        }
        __builtin_amdgcn_sched_barrier(0);
        compute((kb & 1) * BUFB);                 // LDS A(kb) + regs B(kb)
        __builtin_amdgcn_sched_barrier(0);        // pin: refill bb only after last use
        if (kb + 1 < KSTEPS) loadB(kb + 1);
    }

    // ---- epilogue: bias, store y, fused per-channel sum/sumsq ----
    #pragma unroll
    for (int j = 0; j < 4; j++) {
        int col = wn * 64 + j * 16 + lr;
        float bv = bias[col];
        float s = 0.f, s2 = 0.f;
        #pragma unroll
        for (int i = 0; i < 4; i++) {
            int row0 = p0 + wm * 64 + i * 16 + lq * 4;
            #pragma unroll
            for (int r = 0; r < 4; r++) {
                float v = acc[i][j][r] + bv;
                y[(size_t)(row0 + r) * COUT + col] = v;
                s += v; s2 += v * v;
            }
        }
        s  += __shfl_down(s, 32);  s  += __shfl_down(s, 16);
        s2 += __shfl_down(s2, 32); s2 += __shfl_down(s2, 16);
        if (lane < 16) {
            atomicAdd(&stats[col], s);
            atomicAdd(&stats[COUT + col], s2);
        }
    }
}

// ---------------- fold BN into scale/shift ----------------
template<int COUT>
__global__ void finalize_kernel(const float* __restrict__ stats, const float* __restrict__ gamma,
                                const float* __restrict__ beta, float* __restrict__ ss, int N) {
    int co = threadIdx.x;
    float inv_n = 1.f / (float)N;
    float mu  = stats[co] * inv_n;
    float var = stats[COUT + co] * inv_n - mu * mu;
    float sc  = gamma[co] * rsqrtf(var + BN_EPS);
    ss[co]        = sc;
    ss[COUT + co] = beta[co] - mu * sc;
}

// ---------------- BN + ReLU, emit bf16 into strided (PERZ) layout ----------------
template<int COUT>
__global__ void apply_kernel(const float* __restrict__ y, const float* __restrict__ ss,
                             u16* __restrict__ f, int total4) {
    int i = blockIdx.x * blockDim.x + threadIdx.x;
    if (i >= total4) return;
    constexpr int E4 = COUT / 4;
    float4 v = ((const float4*)y)[i];
    int p = i / E4, k = i - p * E4;
    int c0 = k * 4;
    int b = p / PER, r = p - b * PER;
    ushort4 o;
    float a;
    a = fmaf(v.x, ss[c0 + 0], ss[COUT + c0 + 0]); o.x = f2b(a > 0.f ? a : 0.f);
    a = fmaf(v.y, ss[c0 + 1], ss[COUT + c0 + 1]); o.y = f2b(a > 0.f ? a : 0.f);
    a = fmaf(v.z, ss[c0 + 2], ss[COUT + c0 + 2]); o.z = f2b(a > 0.f ? a : 0.f);
    a = fmaf(v.w, ss[c0 + 3], ss[COUT + c0 + 3]); o.w = f2b(a > 0.f ? a : 0.f);
    ((ushort4*)f)[(size_t)(b * PERZ + r) * E4 + k] = o;
}

// ---------------- legacy dense NCDHW output (from bf16 fbuf) ----------------
__global__ void output_kernel(const u16* __restrict__ f, const int* __restrict__ map,
                              float* __restrict__ out, int total) {
    int i = blockIdx.x * blockDim.x + threadIdx.x;
    if (i >= total) return;
    int voxel = i % VOX;
    int bc    = i / VOX;
    int c = bc & 63;
    int b = bc >> 6;
    int p = map[b * VOX + voxel];
    float v = 0.f;
    if (p >= 0) {
        int r = p - b * PER;
        v = b2f(f[(size_t)(b * PERZ + r) * 64 + c]);
    }
    out[i] = v;
}

// ---------------- fused BN+ReLU+scatter to dense NCDHW (LDS transpose, all-coalesced) ----
// Used when workspace is roomy enough for a separate y3 (layer-3 conv output must not
// alias d_out here). One block = (batch b, 64-voxel chunk).
__global__ void output_fused_kernel(const float* __restrict__ y, const float* __restrict__ ss,
                                    const int* __restrict__ map, float* __restrict__ out) {
    __shared__ float tile[64][65];                // [voxel][c], +1 pad
    __shared__ int   prow[64];
    const int chunk = blockIdx.x;                 // BATCH * (VOX/64)
    const int b  = chunk / (VOX / 64);
    const int v0 = (chunk % (VOX / 64)) * 64;
    const int t = threadIdx.x;                    // 256
    if (t < 64) prow[t] = map[b * VOX + v0 + t];
    __syncthreads();
    const int c = t & 63;
    const float sc = ss[c], sh = ss[64 + c];
    for (int v = t >> 6; v < 64; v += 4) {
        int p = prow[v];
        float val = 0.f;
        if (p >= 0) {
            float a = fmaf(y[(size_t)p * 64 + c], sc, sh);
            val = a > 0.f ? a : 0.f;
        }
        tile[v][c] = val;
    }
    __syncthreads();
    const int vv = t & 63;
    #pragma unroll
    for (int cc = t >> 6; cc < 64; cc += 4)
        out[(size_t)(b * 64 + cc) * VOX + v0 + vv] = tile[vv][cc];
}

extern "C" void kernel_launch(void* const* d_in, const int* in_sizes, int n_in,
                              void* d_out, int out_size, void* d_ws, size_t ws_size,
                              hipStream_t stream) {
    const float* feats = (const float*)d_in[0];
    const int*   idx   = (const int*)  d_in[1];
    const float* W0 = (const float*)d_in[3];
    const float* b0 = (const float*)d_in[4];
    const float* g0 = (const float*)d_in[5];
    const float* e0 = (const float*)d_in[6];
    const float* W1 = (const float*)d_in[7];
    const float* b1 = (const float*)d_in[8];
    const float* g1 = (const float*)d_in[9];
    const float* e1 = (const float*)d_in[10];
    const float* W2 = (const float*)d_in[11];
    const float* b2 = (const float*)d_in[12];
    const float* g2 = (const float*)d_in[13];
    const float* e2 = (const float*)d_in[14];

    const int N = in_sizes[0] / 16;               // 442368

    // ---- workspace layout ----
    char* ws = (char*)d_ws;
    size_t off = 0;
    auto alloc = [&](size_t bytes) { void* p = ws + off; off = (off + bytes + 255) & ~(size_t)255; return p; };
    int*   map   = (int*)  alloc((size_t)BATCH * VOX * 4);
    float* stats = (float*)alloc(3 * 256 * 4);
    float* ss    = (float*)alloc(3 * 256 * 4);
    u16*   nbr   = (u16*)  alloc((size_t)N * 32 * 2);
    u16*   wt0   = (u16*)  alloc((size_t)7  * 1 * 512 * 16);    // packed: KSTEPS*NG*512*16B
    u16*   wt1   = (u16*)  alloc((size_t)27 * 2 * 512 * 16);
    u16*   wt2   = (u16*)  alloc((size_t)54 * 1 * 512 * 16);
    u16*   fbuf  = (u16*)  alloc((size_t)BATCH * PERZ * 128 * 2);   // shared by all layers
    float* y = (float*)d_out;                     // fp32 conv out (layers 1/2), aliases d_out

    // layer-3 y gets its own buffer if workspace allows (enables fused output)
    const size_t y3_bytes = (size_t)N * 64 * 4;
    float* y3 = nullptr;
    if (off + y3_bytes <= ws_size) y3 = (float*)alloc(y3_bytes);

    hipMemsetAsync(map,   0xFF, (size_t)BATCH * VOX * 4, stream);
    hipMemsetAsync(stats, 0,    3 * 256 * 4, stream);
    build_map_kernel<<<(N + 255) / 256, 256, 0, stream>>>(idx, map, N);
    build_nbr_kernel<<<(N + 255) / 256, 256, 0, stream>>>(idx, map, nbr, N);
    pack_w_kernel<16,  64 ><<<(7  * 1 * 512 + 255) / 256, 256, 0, stream>>>(W0, wt0);
    pack_w_kernel<64,  128><<<(27 * 2 * 512 + 255) / 256, 256, 0, stream>>>(W1, wt1);
    pack_w_kernel<128, 64 ><<<(54 * 1 * 512 + 255) / 256, 256, 0, stream>>>(W2, wt2);

    // ---- layer 1: 16 -> 64 (BM=256, waves 4x1) ----
    zero_rows_kernel<<<(BATCH * 4 + 255) / 256, 256, 0, stream>>>(fbuf, 16);
    cast_bf16_kernel<<<(N * 4 + 255) / 256, 256, 0, stream>>>(feats, fbuf, N * 4);
    conv_mfma_kernel<16, 64, 256, 4, 1><<<N / 256, 256, 0, stream>>>(fbuf, nbr, wt0, b0, y, stats + 0);
    finalize_kernel<64><<<1, 64, 0, stream>>>(stats + 0, g0, e0, ss + 0, N);
    zero_rows_kernel<<<(BATCH * 16 + 255) / 256, 256, 0, stream>>>(fbuf, 64);
    apply_kernel<64><<<(N * 16 + 255) / 256, 256, 0, stream>>>(y, ss + 0, fbuf, N * 16);

    // ---- layer 2: 64 -> 128 (BM=128, waves 2x2) ----
    conv_mfma_kernel<64, 128, 128, 2, 2><<<N / 128, 256, 0, stream>>>(fbuf, nbr, wt1, b1, y, stats + 256);
    finalize_kernel<128><<<1, 128, 0, stream>>>(stats + 256, g1, e1, ss + 256, N);
    zero_rows_kernel<<<(BATCH * 32 + 255) / 256, 256, 0, stream>>>(fbuf, 128);
    apply_kernel<128><<<(N * 32 + 255) / 256, 256, 0, stream>>>(y, ss + 256, fbuf, N * 32);

    // ---- layer 3: 128 -> 64 (BM=256, waves 4x1) ----
    float* yL3 = y3 ? y3 : y;
    conv_mfma_kernel<128, 64, 256, 4, 1><<<N / 256, 256, 0, stream>>>(fbuf, nbr, wt2, b2, yL3, stats + 512);
    finalize_kernel<64><<<1, 64, 0, stream>>>(stats + 512, g2, e2, ss + 512, N);

    if (y3) {
        // fused BN+ReLU+scatter straight from y3 (no fbuf round-trip)
        output_fused_kernel<<<BATCH * (VOX / 64), 256, 0, stream>>>(y3, ss + 512, map, (float*)d_out);
    } else {
        zero_rows_kernel<<<(BATCH * 16 + 255) / 256, 256, 0, stream>>>(fbuf, 64);
        apply_kernel<64><<<(N * 16 + 255) / 256, 256, 0, stream>>>(y, ss + 512, fbuf, N * 16);
        output_kernel<<<(out_size + 255) / 256, 256, 0, stream>>>(fbuf, map, (float*)d_out, out_size);
    }
}

// Round 8
// 1193.355 us; speedup vs baseline: 1.4592x; 1.1739x over previous
//
#include <hip/hip_runtime.h>

#define DD 12
#define VOX 1728
#define BN_EPS 1e-5f
#define BATCH 512
#define PER 864
#define PERZ 865                                  // PER + 1 zero row per batch
#define NTOT (BATCH * PER)                        // 442368 points

typedef __attribute__((ext_vector_type(8))) short short8;   // 8 bf16 = 16B
typedef __attribute__((ext_vector_type(4))) float f32x4;
typedef unsigned short u16;

__device__ inline u16 f2b(float f) {              // fp32 -> bf16 RNE
    union { float f; unsigned u; } v; v.f = f;
    unsigned r = v.u + 0x7fffu + ((v.u >> 16) & 1u);
    return (u16)(r >> 16);
}
__device__ inline float b2f(u16 h) {
    union { unsigned u; float f; } v; v.u = ((unsigned)h) << 16;
    return v.f;
}
constexpr int ilog2(int v) { return v == 1 ? 0 : 1 + ilog2(v / 2); }

__device__ __forceinline__ void async_copy16(const void* g, void* l) {
    __builtin_amdgcn_global_load_lds(
        (const __attribute__((address_space(1))) void*)g,
        (__attribute__((address_space(3))) void*)l, 16, 0, 0);
}

// counted vmcnt wait; memory clobber pins memory-op motion across it
template<int N> __device__ __forceinline__ void wait_vm() {
    if constexpr (N == 0)       asm volatile("s_waitcnt vmcnt(0)"  ::: "memory");
    else if constexpr (N == 8)  asm volatile("s_waitcnt vmcnt(8)"  ::: "memory");
    else if constexpr (N == 10) asm volatile("s_waitcnt vmcnt(10)" ::: "memory");
    else if constexpr (N == 12) asm volatile("s_waitcnt vmcnt(12)" ::: "memory");
    else if constexpr (N == 18) asm volatile("s_waitcnt vmcnt(18)" ::: "memory");
    else static_assert(N == 0, "unhandled vmcnt value");
}

// ---------------- voxel -> point-row map ----------------
__global__ void build_map_kernel(const int* __restrict__ idx, int* __restrict__ map, int N) {
    int p = blockIdx.x * blockDim.x + threadIdx.x;
    if (p >= N) return;
    const int4 v = ((const int4*)idx)[p];
    map[v.x * VOX + (v.y * DD + v.z) * DD + v.w] = p;
}

// ---------------- neighbor table, TAP-MAJOR: nbr[tap][point] ----------------
// Per-step q loads in the conv kernel read 8 consecutive points at a uniform tap
// -> 1-2 cache lines per instruction instead of 16.
__global__ void build_nbr_kernel(const int* __restrict__ idx, const int* __restrict__ map,
                                 u16* __restrict__ nbr, int N) {
    int p = blockIdx.x * blockDim.x + threadIdx.x;
    if (p >= N) return;
    const int4 v = ((const int4*)idx)[p];
    const int base = v.x * VOX;
    const int lb = v.x * PER;
    #pragma unroll
    for (int nk = 0; nk < 27; nk++) {
        int dz = nk / 9 - 1, dy = (nk / 3) % 3 - 1, dx = nk % 3 - 1;
        int zz = v.y + dz, yy = v.z + dy, xx = v.w + dx;
        u16 out = PER;
        if (zz >= 0 && zz < DD && yy >= 0 && yy < DD && xx >= 0 && xx < DD) {
            int q = map[base + (zz * DD + yy) * DD + xx];
            if (q >= 0) out = (u16)(q - lb);
        }
        nbr[nk * N + p] = out;
    }
    #pragma unroll
    for (int nk = 27; nk < 32; nk++) nbr[nk * N + p] = PER;
}

// ---------------- W [K][COUT] fp32 -> Wt [COUT][Kpad] bf16 (pad pre-zeroed) ----------------
__global__ void transpose_w_kernel(const float* __restrict__ W, u16* __restrict__ Wt,
                                   int K, int COUT, int Kpad) {
    int i = blockIdx.x * blockDim.x + threadIdx.x;
    if (i >= K * COUT) return;
    int n = i % COUT, k = i / COUT;
    Wt[(size_t)n * Kpad + k] = f2b(W[i]);
}

// ---------------- fp32 feats -> bf16, strided (PERZ) layout; zero rows inline ----------
__global__ void cast_bf16_kernel(const float* __restrict__ in, u16* __restrict__ out, int total4) {
    int i = blockIdx.x * blockDim.x + threadIdx.x;          // over BATCH*PERZ*4 (CIN=16)
    if (i >= total4) return;
    int p = i >> 2, c4 = i & 3;
    int b = p / PERZ, r = p - b * PERZ;
    ushort4 o = make_ushort4(0, 0, 0, 0);
    if (r < PER) {
        float4 v = ((const float4*)in)[(size_t)(b * PER + r) * 4 + c4];
        o.x = f2b(v.x); o.y = f2b(v.y); o.z = f2b(v.z); o.w = f2b(v.w);
    }
    ((ushort4*)out)[i] = o;
}

// ---------------- implicit-GEMM conv: R3 structure (best-known) + setprio on MFMA ------
// A+B double-buffered in LDS via global_load_lds, counted vmcnt keeps next-step loads
// in flight across the raw s_barrier; never vmcnt(0) mid-loop. nbr tap-major.
template<int CIN, int COUT, int BM, int WM, int WN>
__global__ __launch_bounds__(256) void conv_mfma_kernel(
    const u16* __restrict__ fin,      // (BATCH*PERZ) x CIN bf16 (zero row per batch)
    const u16* __restrict__ nbr,      // 32 x NTOT u16 (tap-major)
    const u16* __restrict__ Wt,       // COUT x Kpad bf16
    const float* __restrict__ bias,
    float* __restrict__ y,
    float* __restrict__ stats) {
    constexpr int Kpad   = (27 * CIN + 63) & ~63;
    constexpr int KSTEPS = Kpad / 64;
    constexpr int L2C    = ilog2(CIN);
    constexpr int BN     = WN * 64;
    constexpr int ASLOTS = BM / 32;               // per-thread 16B DMA slots for A
    constexpr int BSLOTS = BN / 32;
    constexpr int A_OFF  = BN * 128;              // sB first, then sA (within a buffer)
    constexpr int BUFB   = (BM + BN) * 128;       // one buffer
    static_assert(KSTEPS >= 3, "pipeline prologue needs >=3 K-steps");
    __shared__ char smem[2 * BUFB];               // double-buffered

    // XCD-contiguous swizzle
    const int perx = gridDim.x >> 3;
    const int bid = (blockIdx.x & 7) * perx + (blockIdx.x >> 3);
    const int p0 = bid * BM;

    const int tid = threadIdx.x;
    const int wave = tid >> 6, lane = tid & 63;
    const int wm = wave / WN, wn = wave % WN;     // 64x64 wave tile at (wm*64, wn*64)
    const int lq = lane >> 4, lr = lane & 15;
    const int lrow = lane >> 3;                   // DMA row within 8-row group
    const int kc_d = (lane & 7) ^ (lrow & 7);     // swizzled chunk this lane fetches

    // ---- per-slot invariants ----
    int qvoff[ASLOTS], gbase[ASLOTS];
    #pragma unroll
    for (int i = 0; i < ASLOTS; i++) {
        int m = (wave * ASLOTS + i) * 8 + lrow;
        int p = p0 + m;
        int b = p / PER;
        qvoff[i] = (((kc_d * 8) >> L2C) * NTOT + p) * 2;        // bytes into tap-major nbr
        gbase[i] = b * PERZ * CIN + ((kc_d * 8) & (CIN - 1));   // elems into fin
    }
    int bvoff[BSLOTS];
    #pragma unroll
    for (int j = 0; j < BSLOTS; j++)
        bvoff[j] = ((wave * BSLOTS + j) * 8 + lrow) * Kpad + kc_d * 8;

    // fragment read addrs: physical chunk = logical ^ (row&7)
    int phs[2];
    phs[0] = ((0 + lq) ^ (lr & 7)) * 16;
    phs[1] = ((4 + lq) ^ (lr & 7)) * 16;
    const int aBase = A_OFF + (wm * 64 + lr) * 128;
    const int bBase = (wn * 64 + lr) * 128;

    const f32x4 fzero = {0.f, 0.f, 0.f, 0.f};
    f32x4 acc[4][4];
    #pragma unroll
    for (int i = 0; i < 4; i++)
        #pragma unroll
        for (int j = 0; j < 4; j++) acc[i][j] = fzero;

    u16 q[ASLOTS];
    auto loadQ = [&](int step) {
        int sQ = ((step * 64) >> L2C) * (NTOT * 2);             // tap-major stride
        #pragma unroll
        for (int i = 0; i < ASLOTS; i++)
            q[i] = *(const u16*)((const char*)nbr + qvoff[i] + sQ);
    };
    auto stage = [&](int step, int bo) {
        int sG = (step * 64) & (CIN - 1);
        const u16* fs = fin + sG;
        #pragma unroll
        for (int i = 0; i < ASLOTS; i++)
            async_copy16(fs + gbase[i] + ((int)q[i] << L2C),
                         smem + bo + A_OFF + (wave * ASLOTS + i) * 1024);
        const u16* wsrc = Wt + step * 64;
        #pragma unroll
        for (int j = 0; j < BSLOTS; j++)
            async_copy16(wsrc + bvoff[j], smem + bo + (wave * BSLOTS + j) * 1024);
    };

    // ---- pipeline prologue ----
    loadQ(0);
    stage(0, 0);                                  // buf0 <- step 0
    loadQ(1);                                     // ids for step 1 (in flight)

    #pragma unroll 1
    for (int kb = 0; kb < KSTEPS; kb++) {
        // issue next-step prefetch into the other buffer, then wait (counted) for
        // THIS step's tile; the prefetch stays in flight across the barrier.
        if (kb + 1 < KSTEPS) {
            stage(kb + 1, ((kb + 1) & 1) * BUFB); // q-dep drains stage(kb) implicitly
            if (kb + 2 < KSTEPS) {
                loadQ(kb + 2);
                wait_vm<2 * ASLOTS + BSLOTS>();   // leave stage(kb+1)+loadQ in flight
            } else {
                wait_vm<ASLOTS + BSLOTS>();       // leave stage(kb+1) in flight
            }
        } else {
            wait_vm<0>();                         // last step: drain its tile
        }
        __builtin_amdgcn_s_barrier();             // all waves' tile(kb) landed

        const int so = (kb & 1) * BUFB;
        __builtin_amdgcn_s_setprio(1);            // favor compute-phase wave (T5)
        #pragma unroll
        for (int s = 0; s < 2; s++) {
            short8 af[4], bfr[4];
            #pragma unroll
            for (int i = 0; i < 4; i++)
                af[i] = *(const short8*)(smem + so + aBase + i * 2048 + phs[s]);
            #pragma unroll
            for (int j = 0; j < 4; j++)
                bfr[j] = *(const short8*)(smem + so + bBase + j * 2048 + phs[s]);
            #pragma unroll
            for (int i = 0; i < 4; i++)
                #pragma unroll
                for (int j = 0; j < 4; j++)
                    acc[i][j] = __builtin_amdgcn_mfma_f32_16x16x32_bf16(af[i], bfr[j], acc[i][j], 0, 0, 0);
        }
        __builtin_amdgcn_s_setprio(0);
        asm volatile("s_waitcnt lgkmcnt(0)" ::: "memory");  // all ds_reads retired
        __builtin_amdgcn_s_barrier();             // before buf[kb&1] is overwritten
    }

    // ---- epilogue: bias, store y, fused per-channel sum/sumsq ----
    #pragma unroll
    for (int j = 0; j < 4; j++) {
        int col = wn * 64 + j * 16 + lr;
        float bv = bias[col];
        float s = 0.f, s2 = 0.f;
        #pragma unroll
        for (int i = 0; i < 4; i++) {
            int row0 = p0 + wm * 64 + i * 16 + lq * 4;
            #pragma unroll
            for (int r = 0; r < 4; r++) {
                float v = acc[i][j][r] + bv;
                y[(size_t)(row0 + r) * COUT + col] = v;
                s += v; s2 += v * v;
            }
        }
        s  += __shfl_down(s, 32);  s  += __shfl_down(s, 16);
        s2 += __shfl_down(s2, 32); s2 += __shfl_down(s2, 16);
        if (lane < 16) {
            atomicAdd(&stats[col], s);
            atomicAdd(&stats[COUT + col], s2);
        }
    }
}

// ---------------- fold BN into scale/shift ----------------
template<int COUT>
__global__ void finalize_kernel(const float* __restrict__ stats, const float* __restrict__ gamma,
                                const float* __restrict__ beta, float* __restrict__ ss, int N) {
    int co = threadIdx.x;
    float inv_n = 1.f / (float)N;
    float mu  = stats[co] * inv_n;
    float var = stats[COUT + co] * inv_n - mu * mu;
    float sc  = gamma[co] * rsqrtf(var + BN_EPS);
    ss[co]        = sc;
    ss[COUT + co] = beta[co] - mu * sc;
}

// ---------------- BN + ReLU, emit bf16 into strided (PERZ) layout; zero rows inline ----
template<int COUT>
__global__ void apply_kernel(const float* __restrict__ y, const float* __restrict__ ss,
                             u16* __restrict__ f, int total4) {
    int i = blockIdx.x * blockDim.x + threadIdx.x;          // over BATCH*PERZ*E4
    if (i >= total4) return;
    constexpr int E4 = COUT / 4;
    int p = i / E4, k = i - p * E4;
    int b = p / PERZ, r = p - b * PERZ;
    ushort4 o = make_ushort4(0, 0, 0, 0);
    if (r < PER) {
        float4 v = ((const float4*)y)[(size_t)(b * PER + r) * E4 + k];
        int c0 = k * 4;
        float a;
        a = fmaf(v.x, ss[c0 + 0], ss[COUT + c0 + 0]); o.x = f2b(a > 0.f ? a : 0.f);
        a = fmaf(v.y, ss[c0 + 1], ss[COUT + c0 + 1]); o.y = f2b(a > 0.f ? a : 0.f);
        a = fmaf(v.z, ss[c0 + 2], ss[COUT + c0 + 2]); o.z = f2b(a > 0.f ? a : 0.f);
        a = fmaf(v.w, ss[c0 + 3], ss[COUT + c0 + 3]); o.w = f2b(a > 0.f ? a : 0.f);
    }
    ((ushort4*)f)[i] = o;
}

// ---------------- legacy dense NCDHW output (from bf16 fbuf) ----------------
__global__ void output_kernel(const u16* __restrict__ f, const int* __restrict__ map,
                              float* __restrict__ out, int total) {
    int i = blockIdx.x * blockDim.x + threadIdx.x;
    if (i >= total) return;
    int voxel = i % VOX;
    int bc    = i / VOX;
    int c = bc & 63;
    int b = bc >> 6;
    int p = map[b * VOX + voxel];
    float v = 0.f;
    if (p >= 0) {
        int r = p - b * PER;
        v = b2f(f[(size_t)(b * PERZ + r) * 64 + c]);
    }
    out[i] = v;
}

// ---------------- fused BN+ReLU+scatter to dense NCDHW (LDS transpose, coalesced) ------
// One block = (batch b, 64-voxel chunk); requires layer-3 y in its own buffer.
__global__ void output_fused_kernel(const float* __restrict__ y, const float* __restrict__ ss,
                                    const int* __restrict__ map, float* __restrict__ out) {
    __shared__ float tile[64][65];                // [voxel][c], +1 pad
    __shared__ int   prow[64];
    const int chunk = blockIdx.x;                 // BATCH * (VOX/64)
    const int b  = chunk / (VOX / 64);
    const int v0 = (chunk % (VOX / 64)) * 64;
    const int t = threadIdx.x;                    // 256
    if (t < 64) prow[t] = map[b * VOX + v0 + t];
    __syncthreads();
    const int c = t & 63;
    const float sc = ss[c], sh = ss[64 + c];
    for (int v = t >> 6; v < 64; v += 4) {
        int p = prow[v];
        float val = 0.f;
        if (p >= 0) {
            float a = fmaf(y[(size_t)p * 64 + c], sc, sh);
            val = a > 0.f ? a : 0.f;
        }
        tile[v][c] = val;
    }
    __syncthreads();
    const int vv = t & 63;
    #pragma unroll
    for (int cc = t >> 6; cc < 64; cc += 4)
        out[(size_t)(b * 64 + cc) * VOX + v0 + vv] = tile[vv][cc];
}

extern "C" void kernel_launch(void* const* d_in, const int* in_sizes, int n_in,
                              void* d_out, int out_size, void* d_ws, size_t ws_size,
                              hipStream_t stream) {
    const float* feats = (const float*)d_in[0];
    const int*   idx   = (const int*)  d_in[1];
    const float* W0 = (const float*)d_in[3];
    const float* b0 = (const float*)d_in[4];
    const float* g0 = (const float*)d_in[5];
    const float* e0 = (const float*)d_in[6];
    const float* W1 = (const float*)d_in[7];
    const float* b1 = (const float*)d_in[8];
    const float* g1 = (const float*)d_in[9];
    const float* e1 = (const float*)d_in[10];
    const float* W2 = (const float*)d_in[11];
    const float* b2 = (const float*)d_in[12];
    const float* g2 = (const float*)d_in[13];
    const float* e2 = (const float*)d_in[14];

    const int N = in_sizes[0] / 16;               // 442368

    // ---- workspace layout ----
    char* ws = (char*)d_ws;
    size_t off = 0;
    auto alloc = [&](size_t bytes) { void* p = ws + off; off = (off + bytes + 255) & ~(size_t)255; return p; };
    int*   map   = (int*)  alloc((size_t)BATCH * VOX * 4);
    float* stats = (float*)alloc(3 * 256 * 4);
    float* ss    = (float*)alloc(3 * 256 * 4);
    u16*   nbr   = (u16*)  alloc((size_t)N * 32 * 2);
    u16*   wt0   = (u16*)  alloc((size_t)64  * 448  * 2);
    u16*   wt1   = (u16*)  alloc((size_t)128 * 1728 * 2);
    u16*   wt2   = (u16*)  alloc((size_t)64  * 3456 * 2);
    u16*   fbuf  = (u16*)  alloc((size_t)BATCH * PERZ * 128 * 2);   // shared by all layers
    float* y = (float*)d_out;                     // fp32 conv out (layers 1/2), aliases d_out

    // layer-3 y gets its own buffer if workspace allows (enables fused output)
    const size_t y3_bytes = (size_t)N * 64 * 4;
    float* y3 = nullptr;
    if (off + y3_bytes <= ws_size) y3 = (float*)alloc(y3_bytes);

    hipMemsetAsync(map,   0xFF, (size_t)BATCH * VOX * 4, stream);
    hipMemsetAsync(stats, 0,    3 * 256 * 4, stream);
    hipMemsetAsync(wt0,   0,    (size_t)64 * 448 * 2, stream);      // zero K-pad
    build_map_kernel<<<(N + 255) / 256, 256, 0, stream>>>(idx, map, N);
    build_nbr_kernel<<<(N + 255) / 256, 256, 0, stream>>>(idx, map, nbr, N);
    transpose_w_kernel<<<(432  * 64  + 255) / 256, 256, 0, stream>>>(W0, wt0, 432,  64,  448);
    transpose_w_kernel<<<(1728 * 128 + 255) / 256, 256, 0, stream>>>(W1, wt1, 1728, 128, 1728);
    transpose_w_kernel<<<(3456 * 64  + 255) / 256, 256, 0, stream>>>(W2, wt2, 3456, 64,  3456);

    // ---- layer 1: 16 -> 64 (BM=256, waves 4x1) ----
    cast_bf16_kernel<<<(BATCH * PERZ * 4 + 255) / 256, 256, 0, stream>>>(feats, fbuf, BATCH * PERZ * 4);
    conv_mfma_kernel<16, 64, 256, 4, 1><<<N / 256, 256, 0, stream>>>(fbuf, nbr, wt0, b0, y, stats + 0);
    finalize_kernel<64><<<1, 64, 0, stream>>>(stats + 0, g0, e0, ss + 0, N);
    apply_kernel<64><<<(BATCH * PERZ * 16 + 255) / 256, 256, 0, stream>>>(y, ss + 0, fbuf, BATCH * PERZ * 16);

    // ---- layer 2: 64 -> 128 (BM=128, waves 2x2) ----
    conv_mfma_kernel<64, 128, 128, 2, 2><<<N / 128, 256, 0, stream>>>(fbuf, nbr, wt1, b1, y, stats + 256);
    finalize_kernel<128><<<1, 128, 0, stream>>>(stats + 256, g1, e1, ss + 256, N);
    apply_kernel<128><<<(BATCH * PERZ * 32 + 255) / 256, 256, 0, stream>>>(y, ss + 256, fbuf, BATCH * PERZ * 32);

    // ---- layer 3: 128 -> 64 (BM=256, waves 4x1) ----
    float* yL3 = y3 ? y3 : y;
    conv_mfma_kernel<128, 64, 256, 4, 1><<<N / 256, 256, 0, stream>>>(fbuf, nbr, wt2, b2, yL3, stats + 512);
    finalize_kernel<64><<<1, 64, 0, stream>>>(stats + 512, g2, e2, ss + 512, N);

    if (y3) {
        // fused BN+ReLU+scatter straight from y3 (no fbuf round-trip)
        output_fused_kernel<<<BATCH * (VOX / 64), 256, 0, stream>>>(y3, ss + 512, map, (float*)d_out);
    } else {
        apply_kernel<64><<<(BATCH * PERZ * 16 + 255) / 256, 256, 0, stream>>>(y, ss + 512, fbuf, BATCH * PERZ * 16);
        output_kernel<<<(out_size + 255) / 256, 256, 0, stream>>>(fbuf, map, (float*)d_out, out_size);
    }
}